// Round 8
// baseline (458.142 us; speedup 1.0000x reference)
//
#include <hip/hip_runtime.h>
#include <math.h>

// Problem dims
#define HD    2048
#define QKVD  8192
#define TVD   4096
#define NVHD  32
#define KDD   128
#define VDD   128
#define PROJN (QKVD + TVD + 2*NVHD)   // 12352
#define NB    128                      // 0.5 block/CU -> co-residency guaranteed w/ 2x margin
#define BT    256

typedef float f4 __attribute__((ext_vector_type(4)));

// ---------- helpers ----------
__device__ __forceinline__ float sigmoidf_(float x) { return 1.0f / (1.0f + expf(-x)); }
__device__ __forceinline__ float siluf_(float x)    { return x / (1.0f + expf(-x)); }
__device__ __forceinline__ float softplusf_(float x){ return (x > 20.0f) ? x : log1pf(expf(x)); }
__device__ __forceinline__ float dot4(f4 a, f4 b)   { return a.x*b.x + a.y*b.y + a.z*b.z + a.w*b.w; }
__device__ __forceinline__ f4 ntload(const f4* p)   { return __builtin_nontemporal_load(p); }

__device__ __forceinline__ float waveReduceSum(float v) {
#pragma unroll
    for (int o = 32; o > 0; o >>= 1) v += __shfl_down(v, o, 64);
    return v;
}

template<int NW>
__device__ __forceinline__ float blockReduceSum(float v, float* red) {
    const int lane = threadIdx.x & 63, wid = threadIdx.x >> 6;
    v = waveReduceSum(v);
    if (lane == 0) red[wid] = v;
    __syncthreads();
    float s = 0.f;
#pragma unroll
    for (int w = 0; w < NW; w++) s += red[w];
    __syncthreads();
    return s;
}

// hand-rolled one-shot grid barrier (counters pre-zeroed by init kernel).
// Residency: NB=128 blocks x 4 waves, ~12KB LDS -> all blocks co-resident on
// 256 CUs with >=2x margin regardless of instrumentation.
__device__ __forceinline__ void gridBar(int* bar, int idx) {
    __syncthreads();
    __threadfence();                                  // release (device scope)
    if (threadIdx.x == 0) {
        __hip_atomic_fetch_add(&bar[idx], 1, __ATOMIC_ACQ_REL, __HIP_MEMORY_SCOPE_AGENT);
        while (__hip_atomic_load(&bar[idx], __ATOMIC_ACQUIRE, __HIP_MEMORY_SCOPE_AGENT) < NB)
            __builtin_amdgcn_s_sleep(8);
    }
    __syncthreads();
    __threadfence();                                  // acquire
}

__global__ void init_bar(int* bar) {
    if (threadIdx.x < 8) bar[threadIdx.x] = 0;
}

// ================= fused mega-kernel (round-3 phases + cheap barriers) =================
__global__ __launch_bounds__(BT)
void mega(const float* __restrict__ x, const float* __restrict__ conv_state,
          const float* __restrict__ ssm_state, const float* __restrict__ in_proj_w,
          const float* __restrict__ out_proj_w, const float* __restrict__ conv_weight,
          const float* __restrict__ A_log, const float* __restrict__ dt_bias,
          const float* __restrict__ norm_weight, const float* __restrict__ rms1_w,
          const float* __restrict__ rms2_w, const float* __restrict__ gate_w,
          const float* __restrict__ up_w, const float* __restrict__ down_w,
          float* __restrict__ out0, float* __restrict__ new_conv,
          float* __restrict__ new_ssm, float* __restrict__ proj,
          float* __restrict__ yout, float* __restrict__ x1, float* __restrict__ mmid,
          int* __restrict__ bar) {
    __shared__ float hl[HD];          // staged vector (P0/P1; re-staged P4)
    __shared__ float red[4];
    __shared__ float q_s[KDD], k_s[KDD], v_s[VDD];
    __shared__ float skr2[256], sqr2[256];
    const int t = threadIdx.x, bid = blockIdx.x;
    const int wid = t >> 6, lane = t & 63;

    // ---- P0: rms1 -> hl (per-block; x,w1 are 8KB, L2-hot) ----
    {
        f4 xv[2];
        float s = 0.f;
#pragma unroll
        for (int i = 0; i < 2; i++) {
            xv[i] = ((const f4*)x)[t + i*256];
            s += dot4(xv[i], xv[i]);
        }
        s = blockReduceSum<4>(s, red);
        const float r = rsqrtf(s / (float)HD + 1e-6f);
#pragma unroll
        for (int i = 0; i < 2; i++) {
            f4 wv = ((const f4*)rms1_w)[t + i*256];
            ((f4*)hl)[t + i*256] = xv[i] * r * (wv + 1.0f);
        }
        __syncthreads();
    }

    // ---- P1: in_proj GEMV, 1 wave/row, grid-stride ----
    for (int row = bid*4 + wid; row < PROJN; row += NB*4) {
        const f4* Wr = (const f4*)(in_proj_w + (size_t)row * HD);
        float acc = 0.f;
#pragma unroll
        for (int i = 0; i < 8; i++)
            acc += dot4(ntload(&Wr[lane + i*64]), ((const f4*)hl)[lane + i*64]);
        acc = waveReduceSum(acc);
        if (lane == 0) proj[row] = acc;
    }
    gridBar(bar, 0);

    // ---- P2: blocks 0..31 = SSM per head; others prefetch out_proj_w into LLC ----
    if (bid < NVHD) {
        const int head = bid, qhead = head >> 1;
        float qv = 0.f, kv = 0.f, vv = 0.f;
        if (t < 128) {
            int cq = qhead*KDD + t;
            f4 cs = *(const f4*)(conv_state + (size_t)cq*4);
            f4 w  = *(const f4*)(conv_weight + (size_t)cq*4);
            float xm = proj[cq];
            qv = siluf_(cs.y*w.x + cs.z*w.y + cs.w*w.z + xm*w.w);
            f4 nc; nc.x = cs.y; nc.y = cs.z; nc.z = cs.w; nc.w = xm;
            *(f4*)(new_conv + (size_t)cq*4) = nc;

            int ck = 2048 + qhead*KDD + t;
            cs = *(const f4*)(conv_state + (size_t)ck*4);
            w  = *(const f4*)(conv_weight + (size_t)ck*4);
            xm = proj[ck];
            kv = siluf_(cs.y*w.x + cs.z*w.y + cs.w*w.z + xm*w.w);
            nc.x = cs.y; nc.y = cs.z; nc.z = cs.w; nc.w = xm;
            *(f4*)(new_conv + (size_t)ck*4) = nc;

            int cv = 4096 + head*VDD + t;
            cs = *(const f4*)(conv_state + (size_t)cv*4);
            w  = *(const f4*)(conv_weight + (size_t)cv*4);
            xm = proj[cv];
            vv = siluf_(cs.y*w.x + cs.z*w.y + cs.w*w.z + xm*w.w);
            nc.x = cs.y; nc.y = cs.z; nc.z = cs.w; nc.w = xm;
            *(f4*)(new_conv + (size_t)cv*4) = nc;
        }

        const float sq = blockReduceSum<4>(qv*qv, red);
        const float sk = blockReduceSum<4>(kv*kv, red);
        const float qn = qv / fmaxf(sqrtf(sq), 1e-12f) * 0.08838834764831845f; // *128^-0.5
        const float kn = kv / fmaxf(sqrtf(sk), 1e-12f);
        const float kq = blockReduceSum<4>(qn*kn, red);

        if (t < 128) { q_s[t] = qn; k_s[t] = kn; v_s[t] = vv; }
        __syncthreads();

        const float a_raw = proj[QKVD + TVD + head];
        const float b_raw = proj[QKVD + TVD + NVHD + head];
        const float beta  = sigmoidf_(b_raw);
        const float g     = -expf(A_log[head]) * softplusf_(a_raw + dt_bias[head]);
        const float decay = expf(g);

        const int col = t & 127;
        const int kh  = t >> 7;   // 0 or 1
        const float* Sp = ssm_state + (size_t)head*KDD*VDD + (size_t)kh*64*VDD + col;
        float skr = 0.f, sqr = 0.f;
#pragma unroll 16
        for (int k = 0; k < 64; k++) {
            float sv = Sp[k*VDD];
            skr += sv * k_s[kh*64 + k];
            sqr += sv * q_s[kh*64 + k];
        }
        skr2[t] = skr; sqr2[t] = sqr;
        __syncthreads();
        const float Skr = skr2[col] + skr2[col + 128];
        const float Sqr = sqr2[col] + sqr2[col + 128];
        const float delta = (v_s[col] - decay * Skr) * beta;

        float* Np = new_ssm + (size_t)head*KDD*VDD + (size_t)kh*64*VDD + col;
#pragma unroll 16
        for (int k = 0; k < 64; k++) {
            float sv = Sp[k*VDD];                 // L2-hot re-read
            Np[k*VDD] = decay * sv + k_s[kh*64 + k] * delta;
        }

        const float y = decay * Sqr + delta * kq;
        const float sy = blockReduceSum<4>((kh == 0) ? y*y : 0.f, red);
        if (t < 128) {
            const float rr = rsqrtf(sy / (float)VDD + 1e-6f);
            const float z  = proj[QKVD + head*VDD + t];
            yout[head*VDD + t] = y * rr * norm_weight[t] * siluf_(z);
        }
    } else {
        // prefetch out_proj_w into LLC (overlaps SSM latency phase)
        const f4* P = (const f4*)out_proj_w;
        const int n = HD*TVD/4;
        float acc = 0.f;
        for (int i = (bid - NVHD)*BT + t; i < n; i += (NB - NVHD)*BT) {
            f4 v = P[i];
            acc += v.x + v.y + v.z + v.w;
        }
        asm volatile("" :: "v"(acc));   // keep loads live
    }
    gridBar(bar, 1);

    // ---- P3: out_proj GEMV + residual -> x1 (4 rows/wave; LLC-hot) ----
    {
#pragma unroll
        for (int rr = 0; rr < 4; rr++) {
            const int row = bid*4 + wid + rr*(NB*4);   // 0..2047
            const f4* Wr = (const f4*)(out_proj_w + (size_t)row * TVD);
            const f4* vr = (const f4*)yout;
            float acc = 0.f;
#pragma unroll
            for (int i = 0; i < 16; i++)
                acc += dot4(Wr[lane + i*64], vr[lane + i*64]);
            acc = waveReduceSum(acc);
            if (lane == 0) x1[row] = x[row] + acc;
        }
    }
    gridBar(bar, 2);

    // ---- P4: rms2 prologue (x1 L2-hot) + gate/up dual GEMV ----
    {
        f4 yv[2];
        float s = 0.f;
#pragma unroll
        for (int i = 0; i < 2; i++) {
            yv[i] = ((const f4*)x1)[t + i*256];
            s += dot4(yv[i], yv[i]);
        }
        s = blockReduceSum<4>(s, red);
        const float r = rsqrtf(s / (float)HD + 1e-6f);
#pragma unroll
        for (int i = 0; i < 2; i++) {
            f4 wv = ((const f4*)rms2_w)[t + i*256];
            ((f4*)hl)[t + i*256] = yv[i] * (wv + 1.0f);   // r folded at end
        }
        __syncthreads();

        for (int row = bid*4 + wid; row < 8192; row += NB*4) {
            const f4* Gr = (const f4*)(gate_w + (size_t)row * HD);
            const f4* Ur = (const f4*)(up_w   + (size_t)row * HD);
            float ag = 0.f, au = 0.f;
#pragma unroll
            for (int i = 0; i < 8; i++) {
                f4 tt = ((const f4*)hl)[lane + i*64];
                ag += dot4(ntload(&Gr[lane + i*64]), tt);
                au += dot4(ntload(&Ur[lane + i*64]), tt);
            }
            ag = waveReduceSum(ag);
            au = waveReduceSum(au);
            if (lane == 0) mmid[row] = siluf_(ag * r) * (au * r);
        }
    }
    gridBar(bar, 3);

    // ---- P5: down GEMV + residual -> out (4 rows/wave) ----
    {
#pragma unroll
        for (int rr = 0; rr < 4; rr++) {
            const int row = bid*4 + wid + rr*(NB*4);
            const f4* Wr = (const f4*)(down_w + (size_t)row * 8192);
            const f4* vr = (const f4*)mmid;
            float acc = 0.f;
#pragma unroll 8
            for (int i = 0; i < 32; i++)
                acc += dot4(ntload(&Wr[lane + i*64]), vr[lane + i*64]);
            acc = waveReduceSum(acc);
            if (lane == 0) out0[row] = x1[row] + acc;
        }
    }
}

// ---------- launch ----------
extern "C" void kernel_launch(void* const* d_in, const int* in_sizes, int n_in,
                              void* d_out, int out_size, void* d_ws, size_t ws_size,
                              hipStream_t stream) {
    const float* x           = (const float*)d_in[0];
    const float* conv_state  = (const float*)d_in[1];
    const float* ssm_state   = (const float*)d_in[2];
    const float* in_proj_w   = (const float*)d_in[3];
    const float* out_proj_w  = (const float*)d_in[4];
    const float* conv_weight = (const float*)d_in[5];
    const float* A_log       = (const float*)d_in[6];
    const float* dt_bias     = (const float*)d_in[7];
    const float* norm_weight = (const float*)d_in[8];
    const float* rms1_w      = (const float*)d_in[9];
    const float* rms2_w      = (const float*)d_in[10];
    const float* gate_w      = (const float*)d_in[11];
    const float* up_w        = (const float*)d_in[12];
    const float* down_w      = (const float*)d_in[13];

    float* out0     = (float*)d_out;        // 2048
    float* new_conv = out0 + HD;            // 32768
    float* new_ssm  = new_conv + QKVD*4;    // 524288

    float* ws   = (float*)d_ws;
    float* proj = ws;                 // 12352
    float* yout = proj + PROJN;       // 4096
    float* x1   = yout + TVD;         // 2048
    float* mmid = x1 + HD;            // 8192
    int*   bar  = (int*)(mmid + 8192);

    init_bar<<<1, 64, 0, stream>>>(bar);
    mega<<<NB, BT, 0, stream>>>(x, conv_state, ssm_state, in_proj_w, out_proj_w,
                                conv_weight, A_log, dt_bias, norm_weight,
                                rms1_w, rms2_w, gate_w, up_w, down_w,
                                out0, new_conv, new_ssm, proj, yout, x1, mmid, bar);
}